// Round 7
// baseline (340.574 us; speedup 1.0000x reference)
//
#include <hip/hip_runtime.h>

#define SEQ 2048
#define NH 16
#define HD 64
#define DMODEL 1024

typedef short bf16x8 __attribute__((ext_vector_type(8)));
typedef float f32x16 __attribute__((ext_vector_type(16)));

union FragU {
    bf16x8 v;
    uint4 u4;
    uint2 u2[2];
    unsigned int w[4];
    unsigned short s[8];
};

#if __has_builtin(__builtin_amdgcn_cvt_pk_bf16_f32)
typedef __bf16 v2bf_t __attribute__((ext_vector_type(2)));
__device__ __forceinline__ unsigned int pack_bf16(float lo, float hi) {
    union { v2bf_t h; unsigned int u; } cv;
    cv.h = __builtin_amdgcn_cvt_pk_bf16_f32(lo, hi);
    return cv.u;
}
#else
__device__ __forceinline__ unsigned int pack_bf16(float lo, float hi) {
    unsigned int a = __float_as_uint(lo) + 0x8000u;
    unsigned int b = __float_as_uint(hi) + 0x8000u;
    return __builtin_amdgcn_perm(b, a, 0x07060302);
}
#endif

typedef __attribute__((address_space(1))) const unsigned int glob_u32;
typedef __attribute__((address_space(3))) unsigned int lds_u32;
// async global->LDS DMA, 16B/lane; LDS dest = uniform base + lane*16
__device__ __forceinline__ void dma16(const unsigned short* g, unsigned short* l) {
    __builtin_amdgcn_global_load_lds((glob_u32*)g, (lds_u32*)l, 16, 0, 0);
}

#define EXP_SCALE 1.44269504f   // 1/ln2, folded into Q and bias table
#define LN2       0.69314718f   // folded into epilogue store

// ---------------- prepass: fp32 K,V -> bf16 ws (K row-swizzled; V transposed
// tile-contiguous, row-swizzled). 16B group g of row r stored at g ^ (r&7).
__global__ __launch_bounds__(256)
void prep_kernel(const float* __restrict__ Kg, const float* __restrict__ Vg,
                 unsigned short* __restrict__ wsK, unsigned short* __restrict__ wsVt)
{
    __shared__ unsigned short T[64 * 68];
    const int tid = threadIdx.x;
    const int blk = blockIdx.x;      // 64 bh * 32 tiles
    const int bh  = blk >> 5;
    const int it  = blk & 31;
    const int b = bh >> 4, h = bh & 15;
    const size_t inbase = (size_t)(b * SEQ + it * 64) * DMODEL + h * HD;

    // K: 64 rows x 8 groups, swizzled bf16
    #pragma unroll
    for (int i = 0; i < 2; ++i) {
        int item = tid + i * 256;
        int row = item >> 3, g = item & 7;
        const float* src = Kg + inbase + (size_t)row * DMODEL + g * 8;
        float4 x0 = *(const float4*)src;
        float4 x1 = *(const float4*)(src + 4);
        uint4 w;
        w.x = pack_bf16(x0.x, x0.y); w.y = pack_bf16(x0.z, x0.w);
        w.z = pack_bf16(x1.x, x1.y); w.w = pack_bf16(x1.z, x1.w);
        size_t dst = (size_t)(bh * 2048 + it * 64 + row) * 64 + ((g ^ (row & 7)) * 8);
        *(uint4*)&wsK[dst] = w;
    }
    // V -> LDS transposed bf16 (T[d][kc], stride 68)
    {
        const int kc4 = tid >> 4, d4 = tid & 15;
        float4 a[4];
        #pragma unroll
        for (int r = 0; r < 4; ++r)
            a[r] = *(const float4*)(Vg + inbase + (size_t)(kc4 * 4 + r) * DMODEL + d4 * 4);
        const float* af = (const float*)a;
        #pragma unroll
        for (int c = 0; c < 4; ++c) {
            *(unsigned int*)&T[(d4 * 4 + c) * 68 + kc4 * 4]     = pack_bf16(af[0 * 4 + c], af[1 * 4 + c]);
            *(unsigned int*)&T[(d4 * 4 + c) * 68 + kc4 * 4 + 2] = pack_bf16(af[2 * 4 + c], af[3 * 4 + c]);
        }
    }
    __syncthreads();
    // Vt tile out (64 d-rows x 64 kc), swizzled, 8KB contiguous per tile
    #pragma unroll
    for (int i = 0; i < 2; ++i) {
        int item = tid + i * 256;
        int d = item >> 3, g = item & 7;
        uint2 lo = *(const uint2*)&T[d * 68 + g * 8];
        uint2 hi = *(const uint2*)&T[d * 68 + g * 8 + 4];
        uint4 w; w.x = lo.x; w.y = lo.y; w.z = hi.x; w.w = hi.y;
        size_t dst = (size_t)(bh * 32 + it) * 4096 + d * 64 + ((g ^ (d & 7)) * 8);
        *(uint4*)&wsVt[dst] = w;
    }
}

// ---------------- main: 256 threads = 4 waves, wave = 32q x 64d (block = 128q).
// Grid 1024 = 64 bh x 16 qt -> 4 blocks/CU = 4 independent barrier domains.
// K/Vt tiles DMA'd from ws (bf16, pre-swizzled) into double-buffered LDS,
// one barrier per tile. Bias enters as the MFMA C-operand (no init movs).
// p = x*rcp(1+exp2(-x)); P feeds PV MFMA directly; epilogue * ln2.
__global__ __launch_bounds__(256, 4)
void paa_main(const unsigned short* __restrict__ wsK, const unsigned short* __restrict__ wsVt,
              const float* __restrict__ Qg, const float* __restrict__ RW,
              float* __restrict__ Og)
{
    __shared__ __align__(16) unsigned short KsT[2 * 4096];  // [buf][kc][d-groups swizzled]
    __shared__ __align__(16) unsigned short VtT[2 * 4096];  // [buf][d][kc-groups swizzled]
    __shared__ float btab[128];

    const int tid  = threadIdx.x;
    const int lane = tid & 63;
    const int wave = tid >> 6;   // 0..3
    const int half = lane >> 5;
    const int l31  = lane & 31;
    const int c7   = l31 & 7;

    const int bid  = blockIdx.x;
    const int bh   = bid & 63;   // siblings share XCD (id%8 = bh%8)
    const int qt   = bid >> 6;   // 0..15
    const int b    = bh >> 4;
    const int head = bh & 15;
    const int q0w  = qt * 128 + wave * 32;

    // bias table (pre-scaled by 1/ln2)
    if (tid < 128) {
        int rp = tid;
        int bucket;
        if (rp < 16) bucket = rp;
        else {
            int big = 16 + (int)(logf((float)rp * 0.0625f) * 7.6943736f);
            bucket = big < 31 ? big : 31;
        }
        btab[tid] = RW[bucket * NH + head] * EXP_SCALE;
    }

    // per-lane DMA source pointers (ushort units); tile stride 4096; wave segment 1024
    const unsigned short* kIt = wsK  + (size_t)bh * 131072 + wave * 1024 + lane * 8;
    const unsigned short* vIt = wsVt + (size_t)bh * 131072 + wave * 1024 + lane * 8;

    // prologue: DMA tile 0 into buf 0 (2 segments of 512 ushorts per wave per tensor)
    dma16(kIt,       &KsT[wave * 1024]);
    dma16(kIt + 512, &KsT[wave * 1024 + 512]);
    dma16(vIt,       &VtT[wave * 1024]);
    dma16(vIt + 512, &VtT[wave * 1024 + 512]);

    // preload Q fragments (B operand), pre-scaled by 1/ln2
    FragU qf[4];
    {
        const float* qrow = Qg + (size_t)(b * SEQ + q0w + l31) * DMODEL + head * HD;
        #pragma unroll
        for (int kf = 0; kf < 4; ++kf) {
            int dd = kf * 16 + half * 8;
            float4 x0 = *(const float4*)(qrow + dd);
            float4 x1 = *(const float4*)(qrow + dd + 4);
            FragU f;
            f.w[0] = pack_bf16(x0.x * EXP_SCALE, x0.y * EXP_SCALE);
            f.w[1] = pack_bf16(x0.z * EXP_SCALE, x0.w * EXP_SCALE);
            f.w[2] = pack_bf16(x1.x * EXP_SCALE, x1.y * EXP_SCALE);
            f.w[3] = pack_bf16(x1.z * EXP_SCALE, x1.w * EXP_SCALE);
            qf[kf] = f;
        }
    }

    f32x16 oacc[2];
    #pragma unroll
    for (int n = 0; n < 2; ++n)
        #pragma unroll
        for (int r = 0; r < 16; ++r) oacc[n][r] = 0.0f;

    __syncthreads();   // btab + tile-0 DMA complete
    // preset bias C-operand fragments (held in regs across all tiles)
    f32x16 cb0, cbF;
    {
        const float b0 = btab[0], bF = btab[127];
        #pragma unroll
        for (int r = 0; r < 16; ++r) { cb0[r] = b0; cbF[r] = bF; }
    }

    // per-lane fragment address bases (ushort units within a tile)
    const int kaP = l31 * 64 + c7 * 8;             // ka: row l31, swizzle base
    const int vfP = l31 * 64 + c7 * 8 + half * 4;  // vf: row l31, +inner half*4

    auto compute_tile = [&](const int BUF, const int it) {
        const int kcb = it * 64;
        const unsigned short* kb = &KsT[BUF * 4096];
        const unsigned short* vb = &VtT[BUF * 4096];
        FragU pf[4];
        #pragma unroll
        for (int t = 0; t < 2; ++t) {
            const int kcmin = kcb + t * 32;
            FragU ka[4];
            #pragma unroll
            for (int kf = 0; kf < 4; ++kf) {
                int g8 = (2 * kf + half) * 8;
                ka[kf].u4 = *(const uint4*)&kb[t * 2048 + (kaP ^ g8)];
            }
            // wave-uniform tile case, scalarized
            int tcase = (q0w + 31 <= kcmin) ? 0 : ((q0w - (kcmin + 31) >= 113) ? 1 : 2);
            tcase = __builtin_amdgcn_readfirstlane(tcase);
            f32x16 st;
            if (tcase == 2) {                         // mixed band (~8% of tiles)
                f32x16 bs;
                const int dql = q0w + l31 - kcmin - 4 * half;
                #pragma unroll
                for (int r = 0; r < 16; ++r) {
                    int dv = dql - ((r & 3) + 8 * (r >> 2));
                    dv = dv < 0 ? 0 : (dv > 127 ? 127 : dv);
                    bs[r] = btab[dv];
                }
                st = __builtin_amdgcn_mfma_f32_32x32x16_bf16(ka[0].v, qf[0].v, bs, 0, 0, 0);
            } else if (tcase == 0) {                  // whole tile d<=0
                st = __builtin_amdgcn_mfma_f32_32x32x16_bf16(ka[0].v, qf[0].v, cb0, 0, 0, 0);
            } else {                                  // whole tile bucket 31
                st = __builtin_amdgcn_mfma_f32_32x32x16_bf16(ka[0].v, qf[0].v, cbF, 0, 0, 0);
            }
            #pragma unroll
            for (int kf = 1; kf < 4; ++kf)
                st = __builtin_amdgcn_mfma_f32_32x32x16_bf16(ka[kf].v, qf[kf].v, st, 0, 0, 0);

            // p = x * rcp(1 + exp2(-x))  == 1.4427 * silu(x*ln2)
            float vals[16];
            #pragma unroll
            for (int r = 0; r < 16; ++r) {
                float x = st[r];
                float e = __builtin_amdgcn_exp2f(-x);
                vals[r] = x * __builtin_amdgcn_rcpf(1.0f + e);
            }
            #pragma unroll
            for (int j = 0; j < 4; ++j)
                pf[t * 2].w[j]     = pack_bf16(vals[2 * j], vals[2 * j + 1]);
            #pragma unroll
            for (int j = 0; j < 4; ++j)
                pf[t * 2 + 1].w[j] = pack_bf16(vals[8 + 2 * j], vals[9 + 2 * j]);
        }

        // O += P * V (vf pieces address-matched to P's k-slot permutation)
        #pragma unroll
        for (int f = 0; f < 4; ++f) {
            #pragma unroll
            for (int n = 0; n < 2; ++n) {
                FragU vf;
                const int base = n * 2048;
                vf.u2[0] = *(const uint2*)&vb[base + (vfP ^ (2 * f * 8))];
                vf.u2[1] = *(const uint2*)&vb[base + (vfP ^ ((2 * f + 1) * 8))];
                oacc[n] = __builtin_amdgcn_mfma_f32_32x32x16_bf16(pf[f].v, vf.v, oacc[n], 0, 0, 0);
            }
        }
    };

    for (int it2 = 0; it2 < 16; ++it2) {
        const int it = it2 * 2;
        // even body: DMA tile it+1 -> buf1; compute buf0(tile it)
        kIt += 4096; vIt += 4096;
        dma16(kIt,       &KsT[4096 + wave * 1024]);
        dma16(kIt + 512, &KsT[4096 + wave * 1024 + 512]);
        dma16(vIt,       &VtT[4096 + wave * 1024]);
        dma16(vIt + 512, &VtT[4096 + wave * 1024 + 512]);
        compute_tile(0, it);
        __syncthreads();
        // odd body: DMA tile it+2 -> buf0; compute buf1(tile it+1)
        if (it2 < 15) {
            kIt += 4096; vIt += 4096;
            dma16(kIt,       &KsT[wave * 1024]);
            dma16(kIt + 512, &KsT[wave * 1024 + 512]);
            dma16(vIt,       &VtT[wave * 1024]);
            dma16(vIt + 512, &VtT[wave * 1024 + 512]);
        }
        compute_tile(1, it + 1);
        __syncthreads();
    }

    // store (x ln2): C layout row=q_local, col=d_local
    float* obase = Og + (size_t)(b * SEQ) * DMODEL + head * HD;
    #pragma unroll
    for (int r = 0; r < 16; ++r) {
        int q = q0w + (r & 3) + 8 * (r >> 2) + 4 * half;
        float* orow = obase + (size_t)q * DMODEL;
        #pragma unroll
        for (int n = 0; n < 2; ++n)
            orow[n * 32 + l31] = oacc[n][r] * LN2;
    }
}

extern "C" void kernel_launch(void* const* d_in, const int* in_sizes, int n_in,
                              void* d_out, int out_size, void* d_ws, size_t ws_size,
                              hipStream_t stream) {
    const float* v  = (const float*)d_in[0];
    const float* k  = (const float*)d_in[1];
    const float* q  = (const float*)d_in[2];
    const float* rw = (const float*)d_in[3];
    float* out = (float*)d_out;
    unsigned short* wsK  = (unsigned short*)d_ws;
    unsigned short* wsVt = wsK + (size_t)4 * NH * SEQ * HD;
    prep_kernel<<<dim3(2048), dim3(256), 0, stream>>>(k, v, wsK, wsVt);
    paa_main<<<dim3(1024), dim3(256), 0, stream>>>(wsK, wsVt, q, rw, out);
}

// Round 8
// 224.001 us; speedup vs baseline: 1.5204x; 1.5204x over previous
//
#include <hip/hip_runtime.h>

#define SEQ 2048
#define NH 16
#define HD 64
#define DMODEL 1024

typedef short bf16x8 __attribute__((ext_vector_type(8)));
typedef float f32x16 __attribute__((ext_vector_type(16)));

union FragU {
    bf16x8 v;
    uint4 u4;
    uint2 u2[2];
    unsigned int w[4];
    unsigned short s[8];
};

#if __has_builtin(__builtin_amdgcn_cvt_pk_bf16_f32)
typedef __bf16 v2bf_t __attribute__((ext_vector_type(2)));
__device__ __forceinline__ unsigned int pack_bf16(float lo, float hi) {
    union { v2bf_t h; unsigned int u; } cv;
    cv.h = __builtin_amdgcn_cvt_pk_bf16_f32(lo, hi);
    return cv.u;
}
#else
__device__ __forceinline__ unsigned int pack_bf16(float lo, float hi) {
    unsigned int a = __float_as_uint(lo) + 0x8000u;
    unsigned int b = __float_as_uint(hi) + 0x8000u;
    return __builtin_amdgcn_perm(b, a, 0x07060302);
}
#endif

#define EXP_SCALE 1.44269504f   // 1/ln2, folded into Q and bias table
#define LN2       0.69314718f   // folded into epilogue store

// ---------------- prepass: fp32 K,V -> bf16 fragment-major streams.
// wsK per (bh,tile):  [t][kf][lane][8]: elem j = K[t*32+l31][kf*16 + 8*half + j]
//   (matches Q-fragment k-map d = kf*16 + 8*half + j used in main)
// wsVt per (bh,tile): [f][n][lane][8]: elem j = V[f*16+(j&3)+8*(j>>2)+4*half][n*32+l31]
//   (matches P's C->A k-slot permutation, so PV B-frag is one b128 read)
__global__ __launch_bounds__(256)
void prep_kernel(const float* __restrict__ Kg, const float* __restrict__ Vg,
                 unsigned short* __restrict__ wsK, unsigned short* __restrict__ wsVt)
{
    __shared__ unsigned short Tk[64 * 68];   // [kc][d]
    __shared__ unsigned short Tv[64 * 68];   // [d][kc]
    const int tid = threadIdx.x;
    const int blk = blockIdx.x;      // 64 bh * 32 tiles
    const int bh  = blk >> 5;
    const int it  = blk & 31;
    const int b = bh >> 4, h = bh & 15;
    const size_t inbase = (size_t)(b * SEQ + it * 64) * DMODEL + h * HD;
    const size_t obase  = (size_t)(bh * 32 + it) * 4096;   // ushort units (8KB tiles)

    // K -> Tk[kc][d]
    #pragma unroll
    for (int i = 0; i < 2; ++i) {
        int item = tid + i * 256;
        int row = item >> 3, g = item & 7;
        const float* src = Kg + inbase + (size_t)row * DMODEL + g * 8;
        float4 x0 = *(const float4*)src;
        float4 x1 = *(const float4*)(src + 4);
        uint2 w0, w1;
        w0.x = pack_bf16(x0.x, x0.y); w0.y = pack_bf16(x0.z, x0.w);
        w1.x = pack_bf16(x1.x, x1.y); w1.y = pack_bf16(x1.z, x1.w);
        *(uint2*)&Tk[row * 68 + g * 8]     = w0;
        *(uint2*)&Tk[row * 68 + g * 8 + 4] = w1;
    }
    // V -> Tv[d][kc] (transposed)
    {
        const int kc4 = tid >> 4, d4 = tid & 15;
        float4 a[4];
        #pragma unroll
        for (int r = 0; r < 4; ++r)
            a[r] = *(const float4*)(Vg + inbase + (size_t)(kc4 * 4 + r) * DMODEL + d4 * 4);
        const float* af = (const float*)a;
        #pragma unroll
        for (int c = 0; c < 4; ++c) {
            *(unsigned int*)&Tv[(d4 * 4 + c) * 68 + kc4 * 4]     = pack_bf16(af[0 * 4 + c], af[1 * 4 + c]);
            *(unsigned int*)&Tv[(d4 * 4 + c) * 68 + kc4 * 4 + 2] = pack_bf16(af[2 * 4 + c], af[3 * 4 + c]);
        }
    }
    __syncthreads();

    // K fragment stream out
    #pragma unroll
    for (int i = 0; i < 2; ++i) {
        int o = tid + i * 256;               // 0..511
        int lane_o = o & 63, tk = o >> 6;    // tk = t*4+kf
        int t = tk >> 2, kf = tk & 3;
        int half_o = lane_o >> 5, l31_o = lane_o & 31;
        int pos = (t * 32 + l31_o) * 68 + kf * 16 + half_o * 8;
        uint2 a0 = *(const uint2*)&Tk[pos];
        uint2 a1 = *(const uint2*)&Tk[pos + 4];
        uint4 w; w.x = a0.x; w.y = a0.y; w.z = a1.x; w.w = a1.y;
        *(uint4*)&wsK[obase + (size_t)o * 8] = w;
    }
    // V fragment stream out
    #pragma unroll
    for (int i = 0; i < 2; ++i) {
        int o = tid + i * 256;
        int lane_o = o & 63, fn = o >> 6;    // fn = f*2+n
        int f = fn >> 1, n = fn & 1;
        int half_o = lane_o >> 5, l31_o = lane_o & 31;
        int d = n * 32 + l31_o;
        int p0 = d * 68 + f * 16 + half_o * 4;
        uint2 a0 = *(const uint2*)&Tv[p0];        // kc: 4h+0..3
        uint2 a1 = *(const uint2*)&Tv[p0 + 8];    // kc: 4h+8..11
        uint4 w; w.x = a0.x; w.y = a0.y; w.z = a1.x; w.w = a1.y;
        *(uint4*)&wsVt[obase + (size_t)o * 8] = w;
    }
}

// ---------------- main: 512 threads = 8 waves, wave = 32q x 64d; grid 512
// (64 bh x 8 qt; bid%8=bh%8 keeps each bh's 8 q-blocks on one XCD).
// NO main-loop barriers, NO LDS tiles: K/V fragments are loaded directly from
// the fragment-major ws with lane-linear global_load_dwordx4 (1KB/inst,
// perfectly coalesced); waves run fully decoupled, L1/L2 provide reuse.
// Per-wave loop over 64 half-tiles split into [far-uniform | mixed | near-
// uniform] ranges -> branch-free bodies. Bias enters as the MFMA C operand.
__global__ __launch_bounds__(512, 4)
void paa_main(const unsigned short* __restrict__ wsK, const unsigned short* __restrict__ wsVt,
              const float* __restrict__ Qg, const float* __restrict__ RW,
              float* __restrict__ Og)
{
    __shared__ float btab[128];

    const int tid  = threadIdx.x;
    const int lane = tid & 63;
    const int wave = tid >> 6;   // 0..7
    const int half = lane >> 5;
    const int l31  = lane & 31;

    const int bid  = blockIdx.x;
    const int bh   = bid & 63;
    const int qt   = bid >> 6;   // 0..7
    const int b    = bh >> 4;
    const int head = bh & 15;
    const int q0w  = qt * 256 + wave * 32;

    if (tid < 128) {
        int rp = tid;
        int bucket;
        if (rp < 16) bucket = rp;
        else {
            int big = 16 + (int)(logf((float)rp * 0.0625f) * 7.6943736f);
            bucket = big < 31 ? big : 31;
        }
        btab[tid] = RW[bucket * NH + head] * EXP_SCALE;
    }

    // preload Q fragments (B operand), k-map d = kf*16 + 8*half + j, pre-scaled
    FragU qf[4];
    {
        const float* qrow = Qg + (size_t)(b * SEQ + q0w + l31) * DMODEL + head * HD;
        #pragma unroll
        for (int kf = 0; kf < 4; ++kf) {
            int dd = kf * 16 + half * 8;
            float4 x0 = *(const float4*)(qrow + dd);
            float4 x1 = *(const float4*)(qrow + dd + 4);
            FragU f;
            f.w[0] = pack_bf16(x0.x * EXP_SCALE, x0.y * EXP_SCALE);
            f.w[1] = pack_bf16(x0.z * EXP_SCALE, x0.w * EXP_SCALE);
            f.w[2] = pack_bf16(x1.x * EXP_SCALE, x1.y * EXP_SCALE);
            f.w[3] = pack_bf16(x1.z * EXP_SCALE, x1.w * EXP_SCALE);
            qf[kf] = f;
        }
    }

    f32x16 oacc[2];
    #pragma unroll
    for (int n = 0; n < 2; ++n)
        #pragma unroll
        for (int r = 0; r < 16; ++r) oacc[n][r] = 0.0f;

    __syncthreads();   // btab ready (only barrier in the kernel)
    const float bias_d0  = btab[0];
    const float bias_far = btab[127];

    // fragment stream pointers (ushort units); +2048 per half-tile
    const unsigned short* kp = wsK  + (size_t)bh * 131072 + lane * 8;
    const unsigned short* vp = wsVt + (size_t)bh * 131072 + lane * 8;

    // half-tile body: K frags at kp[kf*512], V frags at vp[fo*1024 + n*512]
    auto do_half = [&](const f32x16& cbias) {
        FragU ka[4];
        #pragma unroll
        for (int kf = 0; kf < 4; ++kf)
            ka[kf].u4 = *(const uint4*)(kp + kf * 512);
        f32x16 st = __builtin_amdgcn_mfma_f32_32x32x16_bf16(ka[0].v, qf[0].v, cbias, 0, 0, 0);
        #pragma unroll
        for (int kf = 1; kf < 4; ++kf)
            st = __builtin_amdgcn_mfma_f32_32x32x16_bf16(ka[kf].v, qf[kf].v, st, 0, 0, 0);
        FragU pf[2];
        #pragma unroll
        for (int r = 0; r < 8; ++r) {
            float x0 = st[2 * r], x1 = st[2 * r + 1];
            float p0 = x0 * __builtin_amdgcn_rcpf(1.0f + __builtin_amdgcn_exp2f(-x0));
            float p1 = x1 * __builtin_amdgcn_rcpf(1.0f + __builtin_amdgcn_exp2f(-x1));
            pf[r >> 2].w[r & 3] = pack_bf16(p0, p1);
        }
        #pragma unroll
        for (int fo = 0; fo < 2; ++fo)
            #pragma unroll
            for (int n = 0; n < 2; ++n) {
                FragU vf;
                vf.u4 = *(const uint4*)(vp + fo * 1024 + n * 512);
                oacc[n] = __builtin_amdgcn_mfma_f32_32x32x16_bf16(pf[fo].v, vf.v, oacc[n], 0, 0, 0);
            }
        kp += 2048; vp += 2048;
    };

    // range split (per-wave; no barriers so per-wave control flow is fine)
    int htFar = (q0w - 112) >> 5; if (htFar < 0) htFar = 0;    // half-tiles all d>=113
    int htD0  = (q0w + 62) >> 5;  if (htD0 > 64) htD0 = 64;    // first half-tile all d<=0

    {   // far-uniform: bias_far
        f32x16 cb;
        #pragma unroll
        for (int r = 0; r < 16; ++r) cb[r] = bias_far;
        for (int ht = 0; ht < htFar; ++ht) do_half(cb);
    }
    {   // mixed band (~5-6 half-tiles): per-element table bias
        for (int ht = htFar; ht < htD0; ++ht) {
            const int kcmin = ht * 32;
            f32x16 bs;
            const int dql = q0w + l31 - kcmin - 4 * half;
            #pragma unroll
            for (int r = 0; r < 16; ++r) {
                int dv = dql - ((r & 3) + 8 * (r >> 2));
                dv = dv < 0 ? 0 : (dv > 127 ? 127 : dv);
                bs[r] = btab[dv];
            }
            do_half(bs);
        }
    }
    {   // near-uniform: bias_d0
        f32x16 cb;
        #pragma unroll
        for (int r = 0; r < 16; ++r) cb[r] = bias_d0;
        for (int ht = htD0; ht < 64; ++ht) do_half(cb);
    }

    // store (x ln2): C layout row=q_local, col=d_local
    float* obase = Og + (size_t)(b * SEQ) * DMODEL + head * HD;
    #pragma unroll
    for (int r = 0; r < 16; ++r) {
        int q = q0w + (r & 3) + 8 * (r >> 2) + 4 * half;
        float* orow = obase + (size_t)q * DMODEL;
        #pragma unroll
        for (int n = 0; n < 2; ++n)
            orow[n * 32 + l31] = oacc[n][r] * LN2;
    }
}

extern "C" void kernel_launch(void* const* d_in, const int* in_sizes, int n_in,
                              void* d_out, int out_size, void* d_ws, size_t ws_size,
                              hipStream_t stream) {
    const float* v  = (const float*)d_in[0];
    const float* k  = (const float*)d_in[1];
    const float* q  = (const float*)d_in[2];
    const float* rw = (const float*)d_in[3];
    float* out = (float*)d_out;
    unsigned short* wsK  = (unsigned short*)d_ws;
    unsigned short* wsVt = wsK + (size_t)4 * NH * SEQ * HD;
    prep_kernel<<<dim3(2048), dim3(256), 0, stream>>>(k, v, wsK, wsVt);
    paa_main<<<dim3(512), dim3(512), 0, stream>>>(wsK, wsVt, q, rw, out);
}